// Round 12
// baseline (259.639 us; speedup 1.0000x reference)
//
#include <hip/hip_runtime.h>
#include <hip/hip_bf16.h>
#include <stdint.h>

#define B_N 16
#define C_N 512
#define S_N 1024
#define G_N 32
#define NH  8
#define HD  64

typedef __attribute__((ext_vector_type(8))) short bf16x8;
typedef __attribute__((ext_vector_type(4))) float f32x4;
typedef __attribute__((ext_vector_type(16))) float f32x16;
typedef unsigned short u16;
typedef unsigned int   u32;
typedef __attribute__((ext_vector_type(4))) u16 u16x4;
typedef __attribute__((ext_vector_type(4))) u32 u32x4;

#define SC2F 0.18033688011112042f   // (1/sqrt(64)) * log2(e), folded into Q

__device__ __forceinline__ u16 f2bf(float f) {
  u32 u = __builtin_bit_cast(u32, f);
  u32 r = (u + 0x7fffu + ((u >> 16) & 1u)) >> 16;   // RNE
  return (u16)r;
}

// single-instruction packed f32x2 -> bf16x2 (a -> low 16, b -> high 16)
__device__ __forceinline__ u32 cvtpk(float a, float b) {
  u32 r;
  asm("v_cvt_pk_bf16_f32 %0, %1, %2" : "=v"(r) : "v"(a), "v"(b));
  return r;
}

__device__ __forceinline__ void gll16(const void* g, void* l) {
  __builtin_amdgcn_global_load_lds((const __attribute__((address_space(1))) u32*)g,
                                   (__attribute__((address_space(3))) u32*)l, 16, 0, 0);
}

// ---------------- GroupNorm stats: one block per (b,g) ----------------
__global__ __launch_bounds__(256) void gn_stats(const float* __restrict__ x,
                                                float* __restrict__ stats) {
  const int bg = blockIdx.x;                    // b*32+g
  const float4* xv = (const float4*)(x + (size_t)bg * (16 * S_N));
  float s = 0.f, ss = 0.f;
  for (int i = threadIdx.x; i < 4096; i += 256) {
    float4 v = xv[i];
    s  += v.x + v.y + v.z + v.w;
    ss += v.x*v.x + v.y*v.y + v.z*v.z + v.w*v.w;
  }
  #pragma unroll
  for (int m = 1; m < 64; m <<= 1) { s += __shfl_xor(s, m); ss += __shfl_xor(ss, m); }
  __shared__ float red[2][4];
  const int wid = threadIdx.x >> 6;
  if ((threadIdx.x & 63) == 0) { red[0][wid] = s; red[1][wid] = ss; }
  __syncthreads();
  if (threadIdx.x == 0) {
    float S1 = red[0][0]+red[0][1]+red[0][2]+red[0][3];
    float S2 = red[1][0]+red[1][1]+red[1][2]+red[1][3];
    float mean = S1 * (1.f/16384.f);
    float var  = S2 * (1.f/16384.f) - mean*mean;
    stats[bg*2]   = mean;
    stats[bg*2+1] = rsqrtf(var + 1e-5f);
  }
}

// ------------- normalize + transpose -> h_t[b][s][c] (bf16) -------------
__global__ __launch_bounds__(256) void gn_apply_t(const float* __restrict__ x,
                                                  const float* __restrict__ stats,
                                                  const float* __restrict__ nw,
                                                  const float* __restrict__ nb,
                                                  u16* __restrict__ h_t) {
  const int c0 = blockIdx.x * 32, s0 = blockIdx.y * 64, b = blockIdx.z;
  __shared__ u16 tile[32][68];
  const int t = threadIdx.x;
  #pragma unroll
  for (int i = 0; i < 2; i++) {
    int idx4 = (i*256 + t) * 4;
    int cr = idx4 >> 6, sr = idx4 & 63;
    int c = c0 + cr;
    float4 v = *(const float4*)&x[((size_t)b*C_N + c)*S_N + s0 + sr];
    int bg = b*G_N + (c >> 4);
    float mean = stats[bg*2], rstd = stats[bg*2+1];
    float w = nw[c]*rstd;
    float bb = nb[c] - mean*w;
    tile[cr][sr]   = f2bf(v.x*w + bb);
    tile[cr][sr+1] = f2bf(v.y*w + bb);
    tile[cr][sr+2] = f2bf(v.z*w + bb);
    tile[cr][sr+3] = f2bf(v.w*w + bb);
  }
  __syncthreads();
  #pragma unroll
  for (int i = 0; i < 2; i++) {
    int idx = i*256 + t;
    int sr = idx >> 3;
    int cr4 = (idx & 7) * 4;
    u16x4 v = { tile[cr4][sr], tile[cr4+1][sr], tile[cr4+2][sr], tile[cr4+3][sr] };
    *(u16x4*)&h_t[((size_t)b*S_N + s0 + sr)*C_N + c0 + cr4] = v;
  }
}

// ---------------- fp32 -> bf16 weight convert (both weights, one launch) ----------------
__global__ __launch_bounds__(256) void cvt_bf16_all(const float* __restrict__ qkvw,
                                                    const float* __restrict__ projw,
                                                    u16* __restrict__ qw,
                                                    u16* __restrict__ pw) {
  int i = blockIdx.x*256 + threadIdx.x;
  const float4* src; u16x4* dst; int j;
  if (i < 196608) { src = (const float4*)qkvw; dst = (u16x4*)qw; j = i; }
  else            { src = (const float4*)projw; dst = (u16x4*)pw; j = i - 196608; }
  float4 v = src[j];
  u16x4 r = { f2bf(v.x), f2bf(v.y), f2bf(v.z), f2bf(v.w) };
  dst[j] = r;
}

// ---------------- GEMM-1: qkv = h_t @ qkv_w^T, scatter to Q/K/V packs ----------------
// Double-buffered LDS, ONE barrier per K-step; stage(k+1) overlaps compute(k).
__global__ __launch_bounds__(256) void gemm_qkv(const u16* __restrict__ h_t,
                                                const u16* __restrict__ wq,
                                                const float* __restrict__ bq,
                                                u16* __restrict__ Qp,
                                                u16* __restrict__ Kp,
                                                u16* __restrict__ Vp) {
  __shared__ u16 Ash[2][128*32];
  __shared__ u16 Bsh[2][128*32];
  const int n0 = blockIdx.x*128, m0 = blockIdx.y*128, b = blockIdx.z;
  const int tid = threadIdx.x, wid = tid >> 6, lane = tid & 63;
  const int wm = wid >> 1, wn = wid & 1;
  const u16* Ag = h_t + (size_t)b*S_N*C_N;
  const f32x4 vzero = {0.f,0.f,0.f,0.f};
  f32x4 acc[4][4];
  #pragma unroll
  for (int i=0;i<4;i++)
    #pragma unroll
    for (int j=0;j<4;j++) acc[i][j] = vzero;

  const int arow = lane >> 2, aslot = (lane & 3) * 8;

  auto stage = [&](u16* Adst, u16* Bdst, int k0s) {
    #pragma unroll
    for (int i = 0; i < 2; i++) {
      int r = wid*32 + i*16 + arow;
      gll16(Ag + (size_t)(m0+r)*C_N + k0s + aslot, &Adst[(wid*32+i*16)*32]);
      gll16(wq + (size_t)(n0+r)*C_N + k0s + aslot, &Bdst[(wid*32+i*16)*32]);
    }
  };
  auto compute = [&](const u16* AshC, const u16* BshC) {
    bf16x8 aF[4], bF[4];
    #pragma unroll
    for (int mi=0;mi<4;mi++)
      aF[mi] = *(const bf16x8*)&AshC[(wm*64+mi*16+(lane&15))*32 + (lane>>4)*8];
    #pragma unroll
    for (int ni=0;ni<4;ni++)
      bF[ni] = *(const bf16x8*)&BshC[(wn*64+ni*16+(lane&15))*32 + (lane>>4)*8];
    #pragma unroll
    for (int mi=0;mi<4;mi++)
      #pragma unroll
      for (int ni=0;ni<4;ni++)
        acc[mi][ni] = __builtin_amdgcn_mfma_f32_16x16x32_bf16(aF[mi], bF[ni], acc[mi][ni], 0, 0, 0);
  };

  stage(Ash[0], Bsh[0], 0);
  #pragma unroll 1
  for (int k0 = 0; k0 < C_N; k0 += 64) {
    asm volatile("s_waitcnt vmcnt(0)" ::: "memory");
    __syncthreads();
    stage(Ash[1], Bsh[1], k0 + 32);
    compute(Ash[0], Bsh[0]);
    asm volatile("s_waitcnt vmcnt(0)" ::: "memory");
    __syncthreads();
    if (k0 + 64 < C_N) stage(Ash[0], Bsh[0], k0 + 64);
    compute(Ash[1], Bsh[1]);
  }

  #pragma unroll
  for (int mi=0;mi<4;mi++) {
    #pragma unroll
    for (int ni=0;ni<4;ni++) {
      int o = n0 + wn*64 + ni*16 + (lane & 15);
      float bias = bq[o];
      int sec = o >> 9;
      int oo  = o & 511;
      int hh  = oo >> 6, d = oo & 63;
      size_t bh = (size_t)(b*NH + hh);
      float qsc = (sec == 0) ? SC2F : 1.0f;
      #pragma unroll
      for (int r=0;r<4;r++) {
        int s = m0 + wm*64 + mi*16 + (lane>>4)*4 + r;
        u16 bv = f2bf((acc[mi][ni][r] + bias) * qsc);
        if (sec == 0)      Qp[(bh*S_N + s)*HD + d] = bv;
        else if (sec == 1) Kp[(bh*S_N + s)*HD + d] = bv;
        else               Vp[(bh*HD + d)*S_N + s] = bv;
      }
    }
  }
}

// ---------------- flash attention: 32x32 swapped, K/V LDS-staged, 1-barrier 2-phase ----------------
// {vmcnt(0); barrier; stage(next->other buf); compute(cur)} — the single barrier both
// publishes tile i and closes tile i-1's readers before its buffer is restaged.
__device__ __forceinline__ void attn_tile_body(const u16* __restrict__ Kb,
                                               const u16* __restrict__ Vb,
                                               u16* __restrict__ KlC, u16* __restrict__ VlC,   // current buffers
                                               u16* __restrict__ KlN, u16* __restrict__ VlN,   // next buffers
                                               const bf16x8 (&qf)[4], const bf16x8 onesf,
                                               f32x16 (&oacc)[2], f32x16& oacc_l,
                                               int it, int l31, int hi,
                                               int ra, int rb, int ca, int cb, int wid) {
  const int t0 = it * 64;
  asm volatile("s_waitcnt vmcnt(0)" ::: "memory");   // my slice of tile `it` landed
  __syncthreads();                                    // tile `it` visible; tile it-1 readers closed

  // stage NEXT tile — overlaps all compute below
  if (it < 15) {
    const int tn = t0 + 64;
    gll16(Kb + (size_t)(tn + ra)*HD + ca, &KlN[(wid*16    )*64]);
    gll16(Kb + (size_t)(tn + rb)*HD + cb, &KlN[(wid*16 + 8)*64]);
    gll16(Vb + (size_t)ra*S_N + tn + ca,  &VlN[(wid*16    )*64]);
    gll16(Vb + (size_t)rb*S_N + tn + cb,  &VlN[(wid*16 + 8)*64]);
  }

  // K fragments: row = tt*32+l31, logical slot kt*2+hi, phys = slot^(row&7)
  bf16x8 kF[2][4];
  #pragma unroll
  for (int tt=0;tt<2;tt++)
    #pragma unroll
    for (int kt=0;kt<4;kt++) {
      int row = tt*32 + l31;
      int phys = (kt*2 + hi) ^ (row & 7);
      kF[tt][kt] = *(const bf16x8*)&KlC[row*64 + phys*8];
    }

  // QK^T: st[tt][reg] = S[t][s], t=(reg&3)+8*(reg>>2)+4*hi+32*tt
  f32x16 st[2];
  #pragma unroll
  for (int tt=0;tt<2;tt++)
    #pragma unroll
    for (int i=0;i<16;i++) st[tt][i] = 0.f;
  __builtin_amdgcn_s_setprio(1);
  #pragma unroll
  for (int tt=0;tt<2;tt++)
    #pragma unroll
    for (int kt=0;kt<4;kt++)
      st[tt] = __builtin_amdgcn_mfma_f32_32x32x16_bf16(kF[tt][kt], qf[kt], st[tt], 0, 0, 0);
  __builtin_amdgcn_s_setprio(0);

  // p = exp2(S) in place (Q pre-scaled)
  #pragma unroll
  for (int tt=0;tt<2;tt++)
    #pragma unroll
    for (int i=0;i<16;i++)
      st[tt][i] = exp2f(st[tt][i]);

  // assemble P^T B-fragments: pa[ks] elem j <-> t = ks*16 + hi*8 + j
  u32x4 paw[4];
  #pragma unroll
  for (int ks=0;ks<4;ks++) {
    float p0 = st[ks>>1][(ks&1)*8+0], p1 = st[ks>>1][(ks&1)*8+1];
    float p2 = st[ks>>1][(ks&1)*8+2], p3 = st[ks>>1][(ks&1)*8+3];
    float p4 = st[ks>>1][(ks&1)*8+4], p5 = st[ks>>1][(ks&1)*8+5];
    float p6 = st[ks>>1][(ks&1)*8+6], p7 = st[ks>>1][(ks&1)*8+7];
    u32 w0 = cvtpk(p0, p1);
    u32 w1 = cvtpk(p2, p3);
    u32 w2 = cvtpk(p4, p5);
    u32 w3 = cvtpk(p6, p7);
    u32 s0 = hi ? w0 : w2;               // word my partner needs
    u32 s1 = hi ? w1 : w3;
    u32 r0 = (u32)__shfl_xor((int)s0, 32);
    u32 r1 = (u32)__shfl_xor((int)s1, 32);
    u32x4 w = { hi ? r0 : w0, hi ? r1 : w1, hi ? w2 : r0, hi ? w3 : r1 };
    paw[ks] = w;
  }

  // PV + l-sum: V fragments just-in-time; l via ones-MFMA (all 16 regs identical)
  __builtin_amdgcn_s_setprio(1);
  #pragma unroll
  for (int ks=0;ks<4;ks++) {
    bf16x8 pb = __builtin_bit_cast(bf16x8, paw[ks]);
    oacc_l = __builtin_amdgcn_mfma_f32_32x32x16_bf16(onesf, pb, oacc_l, 0, 0, 0);
    #pragma unroll
    for (int dt=0;dt<2;dt++) {
      int row = dt*32 + l31;
      int phys = (ks*2 + hi) ^ (row & 7);
      bf16x8 vF = *(const bf16x8*)&VlC[row*64 + phys*8];
      oacc[dt] = __builtin_amdgcn_mfma_f32_32x32x16_bf16(vF, pb, oacc[dt], 0, 0, 0);
    }
  }
  __builtin_amdgcn_s_setprio(0);
  // no trailing barrier: next iter's {vmcnt; barrier} closes this tile's reads
}

__global__ __launch_bounds__(256) void attn_fwd(const u16* __restrict__ Qp,
                                                const u16* __restrict__ Kp,
                                                const u16* __restrict__ Vp,
                                                u16* __restrict__ at) {
  __shared__ u16 Kl[2][64*64];   // [t][d] rows 128B, 16B-slot XOR'd by (t&7)
  __shared__ u16 Vl[2][64*64];   // [d][t] rows 128B, 16B-slot XOR'd by (d&7)
  const int hh = blockIdx.x, q0 = blockIdx.y*128, b = blockIdx.z;
  const int tid = threadIdx.x, wid = tid >> 6, lane = tid & 63;
  const int l31 = lane & 31, hi = lane >> 5;
  const size_t bh = (size_t)(b*NH + hh);
  const u16* Qb = Qp + bh*(S_N*HD);
  const u16* Kb = Kp + bh*(S_N*HD);
  const u16* Vb = Vp + bh*(HD*S_N);
  const int s = q0 + wid*32 + l31;          // this lane's s-row

  // Q B-fragments: Q[s][kt*16 + hi*8 + j]
  bf16x8 qf[4];
  #pragma unroll
  for (int kt=0;kt<4;kt++)
    qf[kt] = *(const bf16x8*)&Qb[(size_t)s*HD + kt*16 + hi*8];

  const u32x4 onesw = {0x3F803F80u, 0x3F803F80u, 0x3F803F80u, 0x3F803F80u};
  const bf16x8 onesf = __builtin_bit_cast(bf16x8, onesw);

  f32x16 oacc[2], oacc_l;
  #pragma unroll
  for (int dt=0;dt<2;dt++)
    #pragma unroll
    for (int i=0;i<16;i++) oacc[dt][i] = 0.f;
  #pragma unroll
  for (int i=0;i<16;i++) oacc_l[i] = 0.f;

  // staging geometry: row = wid*16 + {0,8} + (lane>>3), source slot = (lane&7)^(row&7)
  const int ra = wid*16 + (lane >> 3);
  const int rb = ra + 8;
  const int ca = (((lane & 7) ^ (ra & 7)) * 8);
  const int cb = (((lane & 7) ^ (rb & 7)) * 8);

  // prologue: stage tile 0 into buffer 0
  gll16(Kb + (size_t)ra*HD + ca,  &Kl[0][(wid*16    )*64]);
  gll16(Kb + (size_t)rb*HD + cb,  &Kl[0][(wid*16 + 8)*64]);
  gll16(Vb + (size_t)ra*S_N + ca, &Vl[0][(wid*16    )*64]);
  gll16(Vb + (size_t)rb*S_N + cb, &Vl[0][(wid*16 + 8)*64]);

  #pragma unroll 1
  for (int it = 0; it < 16; it += 2) {
    attn_tile_body(Kb, Vb, Kl[0], Vl[0], Kl[1], Vl[1], qf, onesf, oacc, oacc_l,
                   it,     l31, hi, ra, rb, ca, cb, wid);
    attn_tile_body(Kb, Vb, Kl[1], Vl[1], Kl[0], Vl[0], qf, onesf, oacc, oacc_l,
                   it + 1, l31, hi, ra, rb, ca, cb, wid);
  }

  // l is complete (ones-MFMA contracts both halves); all oacc_l regs identical
  float inv = 1.0f / oacc_l[0];
  #pragma unroll
  for (int dt=0;dt<2;dt++)
    #pragma unroll
    for (int qd=0;qd<4;qd++) {
      int dbase = 4*hi + 8*qd + 32*dt;
      u16x4 o;
      #pragma unroll
      for (int j=0;j<4;j++) o[j] = f2bf(oacc[dt][qd*4+j] * inv);
      *(u16x4*)&at[((size_t)b*S_N + s)*C_N + hh*HD + dbase] = o;
    }
}

// ---------------- GEMM-2: out = proj_w @ attn + bias + x ----------------
// Double-buffered LDS, ONE barrier per K-step; stage(k+1) overlaps compute(k).
__global__ __launch_bounds__(256) void gemm_proj(const u16* __restrict__ pwb,
                                                 const u16* __restrict__ at,
                                                 const float* __restrict__ bp,
                                                 const float* __restrict__ x,
                                                 float* __restrict__ out) {
  __shared__ u16 Ash[2][128*32];
  __shared__ u16 Bsh[2][128*32];
  const int n0 = blockIdx.x*128, m0 = blockIdx.y*128, b = blockIdx.z;
  const int tid = threadIdx.x, wid = tid >> 6, lane = tid & 63;
  const int wm = wid >> 1, wn = wid & 1;
  const u16* Bg = at + (size_t)b*S_N*C_N;
  const f32x4 vzero = {0.f,0.f,0.f,0.f};
  f32x4 acc[4][4];
  #pragma unroll
  for (int i=0;i<4;i++)
    #pragma unroll
    for (int j=0;j<4;j++) acc[i][j] = vzero;

  const int arow = lane >> 2, aslot = (lane & 3) * 8;

  auto stage = [&](u16* Adst, u16* Bdst, int k0s) {
    #pragma unroll
    for (int i = 0; i < 2; i++) {
      int r = wid*32 + i*16 + arow;
      gll16(pwb + (size_t)(m0+r)*C_N + k0s + aslot, &Adst[(wid*32+i*16)*32]);
      gll16(Bg  + (size_t)(n0+r)*C_N + k0s + aslot, &Bdst[(wid*32+i*16)*32]);
    }
  };
  auto compute = [&](const u16* AshC, const u16* BshC) {
    bf16x8 aF[4], bF[4];
    #pragma unroll
    for (int mi=0;mi<4;mi++)
      aF[mi] = *(const bf16x8*)&AshC[(wm*64+mi*16+(lane&15))*32 + (lane>>4)*8];
    #pragma unroll
    for (int ni=0;ni<4;ni++)
      bF[ni] = *(const bf16x8*)&BshC[(wn*64+ni*16+(lane&15))*32 + (lane>>4)*8];
    #pragma unroll
    for (int mi=0;mi<4;mi++)
      #pragma unroll
      for (int ni=0;ni<4;ni++)
        acc[mi][ni] = __builtin_amdgcn_mfma_f32_16x16x32_bf16(aF[mi], bF[ni], acc[mi][ni], 0, 0, 0);
  };

  stage(Ash[0], Bsh[0], 0);
  #pragma unroll 1
  for (int k0 = 0; k0 < C_N; k0 += 64) {
    asm volatile("s_waitcnt vmcnt(0)" ::: "memory");
    __syncthreads();
    stage(Ash[1], Bsh[1], k0 + 32);
    compute(Ash[0], Bsh[0]);
    asm volatile("s_waitcnt vmcnt(0)" ::: "memory");
    __syncthreads();
    if (k0 + 64 < C_N) stage(Ash[0], Bsh[0], k0 + 64);
    compute(Ash[1], Bsh[1]);
  }

  #pragma unroll
  for (int mi=0;mi<4;mi++) {
    #pragma unroll
    for (int ni=0;ni<4;ni++) {
      int ss = n0 + wn*64 + ni*16 + (lane & 15);
      #pragma unroll
      for (int r=0;r<4;r++) {
        int o = m0 + wm*64 + mi*16 + (lane>>4)*4 + r;
        size_t idx = ((size_t)b*C_N + o)*S_N + ss;
        out[idx] = acc[mi][ni][r] + bp[o] + x[idx];
      }
    }
  }
}

extern "C" void kernel_launch(void* const* d_in, const int* in_sizes, int n_in,
                              void* d_out, int out_size, void* d_ws, size_t ws_size,
                              hipStream_t stream) {
  const float* x     = (const float*)d_in[0];
  const float* nw    = (const float*)d_in[1];
  const float* nb    = (const float*)d_in[2];
  const float* qkvw  = (const float*)d_in[3];
  const float* qkvb  = (const float*)d_in[4];
  const float* projw = (const float*)d_in[5];
  const float* projb = (const float*)d_in[6];
  float* out = (float*)d_out;

  char* ws = (char*)d_ws;
  float* stats = (float*)ws;                              //   4 KB
  u16* h_t = (u16*)(ws + 4096);                           //  16 MB  [B][S][C]
  u16* qw  = (u16*)(ws + 4096 + 16777216);                // 1.5 MB  [1536][512]
  u16* pw  = (u16*)((char*)qw + 1572864);                 // 0.5 MB  [512][512]
  u16* Qp  = (u16*)((char*)pw + 524288);                  //  16 MB  [B][NH][S][HD]
  u16* Kp  = (u16*)((char*)Qp + 16777216);                //  16 MB  [B][NH][S][HD]
  u16* Vp  = (u16*)((char*)Kp + 16777216);                //  16 MB  [B][NH][HD][S]
  u16* at  = (u16*)((char*)Vp + 16777216);                //  16 MB  [B][S][C]

  gn_stats    <<<512, 256, 0, stream>>>(x, stats);
  gn_apply_t  <<<dim3(16,16,16), 256, 0, stream>>>(x, stats, nw, nb, h_t);
  cvt_bf16_all<<<1024, 256, 0, stream>>>(qkvw, projw, qw, pw);
  gemm_qkv    <<<dim3(12,8,16), 256, 0, stream>>>(h_t, qw, qkvb, Qp, Kp, Vp);
  attn_fwd    <<<dim3(8,8,16), 256, 0, stream>>>(Qp, Kp, Vp, at);
  gemm_proj   <<<dim3(8,4,16), 256, 0, stream>>>(pw, at, projb, x, out);
}

// Round 13
// 255.009 us; speedup vs baseline: 1.0182x; 1.0182x over previous
//
#include <hip/hip_runtime.h>
#include <hip/hip_bf16.h>
#include <stdint.h>

#define B_N 16
#define C_N 512
#define S_N 1024
#define G_N 32
#define NH  8
#define HD  64

typedef __attribute__((ext_vector_type(8))) short bf16x8;
typedef __attribute__((ext_vector_type(4))) float f32x4;
typedef __attribute__((ext_vector_type(16))) float f32x16;
typedef unsigned short u16;
typedef unsigned int   u32;
typedef __attribute__((ext_vector_type(4))) u16 u16x4;
typedef __attribute__((ext_vector_type(4))) u32 u32x4;

#define SC2F 0.18033688011112042f   // (1/sqrt(64)) * log2(e), folded into Q

__device__ __forceinline__ u16 f2bf(float f) {
  u32 u = __builtin_bit_cast(u32, f);
  u32 r = (u + 0x7fffu + ((u >> 16) & 1u)) >> 16;   // RNE
  return (u16)r;
}

// single-instruction packed f32x2 -> bf16x2 (a -> low 16, b -> high 16)
__device__ __forceinline__ u32 cvtpk(float a, float b) {
  u32 r;
  asm("v_cvt_pk_bf16_f32 %0, %1, %2" : "=v"(r) : "v"(a), "v"(b));
  return r;
}

__device__ __forceinline__ void gll16(const void* g, void* l) {
  __builtin_amdgcn_global_load_lds((const __attribute__((address_space(1))) u32*)g,
                                   (__attribute__((address_space(3))) u32*)l, 16, 0, 0);
}

// ---------------- GroupNorm stats (blocks 0..511) + weight bf16 convert (blocks 512..1535) ----------------
__global__ __launch_bounds__(256) void gn_stats_cvt(const float* __restrict__ x,
                                                    float* __restrict__ stats,
                                                    const float* __restrict__ qkvw,
                                                    const float* __restrict__ projw,
                                                    u16* __restrict__ qw,
                                                    u16* __restrict__ pw) {
  const int blk = blockIdx.x;
  if (blk < 512) {
    const int bg = blk;                         // b*32+g
    const float4* xv = (const float4*)(x + (size_t)bg * (16 * S_N));
    float s = 0.f, ss = 0.f;
    for (int i = threadIdx.x; i < 4096; i += 256) {
      float4 v = xv[i];
      s  += v.x + v.y + v.z + v.w;
      ss += v.x*v.x + v.y*v.y + v.z*v.z + v.w*v.w;
    }
    #pragma unroll
    for (int m = 1; m < 64; m <<= 1) { s += __shfl_xor(s, m); ss += __shfl_xor(ss, m); }
    __shared__ float red[2][4];
    const int wid = threadIdx.x >> 6;
    if ((threadIdx.x & 63) == 0) { red[0][wid] = s; red[1][wid] = ss; }
    __syncthreads();
    if (threadIdx.x == 0) {
      float S1 = red[0][0]+red[0][1]+red[0][2]+red[0][3];
      float S2 = red[1][0]+red[1][1]+red[1][2]+red[1][3];
      float mean = S1 * (1.f/16384.f);
      float var  = S2 * (1.f/16384.f) - mean*mean;
      stats[bg*2]   = mean;
      stats[bg*2+1] = rsqrtf(var + 1e-5f);
    }
  } else {
    int i = (blk - 512)*256 + threadIdx.x;      // exactly 262144 = 196608 + 65536
    const float4* src; u16x4* dst; int j;
    if (i < 196608) { src = (const float4*)qkvw;  dst = (u16x4*)qw; j = i; }
    else            { src = (const float4*)projw; dst = (u16x4*)pw; j = i - 196608; }
    float4 v = src[j];
    u16x4 r = { f2bf(v.x), f2bf(v.y), f2bf(v.z), f2bf(v.w) };
    dst[j] = r;
  }
}

// ------------- normalize + transpose -> h_t[b][s][c] (bf16) -------------
__global__ __launch_bounds__(256) void gn_apply_t(const float* __restrict__ x,
                                                  const float* __restrict__ stats,
                                                  const float* __restrict__ nw,
                                                  const float* __restrict__ nb,
                                                  u16* __restrict__ h_t) {
  const int c0 = blockIdx.x * 32, s0 = blockIdx.y * 64, b = blockIdx.z;
  __shared__ u16 tile[32][68];
  const int t = threadIdx.x;
  #pragma unroll
  for (int i = 0; i < 2; i++) {
    int idx4 = (i*256 + t) * 4;
    int cr = idx4 >> 6, sr = idx4 & 63;
    int c = c0 + cr;
    float4 v = *(const float4*)&x[((size_t)b*C_N + c)*S_N + s0 + sr];
    int bg = b*G_N + (c >> 4);
    float mean = stats[bg*2], rstd = stats[bg*2+1];
    float w = nw[c]*rstd;
    float bb = nb[c] - mean*w;
    tile[cr][sr]   = f2bf(v.x*w + bb);
    tile[cr][sr+1] = f2bf(v.y*w + bb);
    tile[cr][sr+2] = f2bf(v.z*w + bb);
    tile[cr][sr+3] = f2bf(v.w*w + bb);
  }
  __syncthreads();
  #pragma unroll
  for (int i = 0; i < 2; i++) {
    int idx = i*256 + t;
    int sr = idx >> 3;
    int cr4 = (idx & 7) * 4;
    u16x4 v = { tile[cr4][sr], tile[cr4+1][sr], tile[cr4+2][sr], tile[cr4+3][sr] };
    *(u16x4*)&h_t[((size_t)b*S_N + s0 + sr)*C_N + c0 + cr4] = v;
  }
}

// ---------------- GEMM-1: qkv = h_t @ qkv_w^T, scatter to Q/K/V packs ----------------
// Double-buffered LDS, ONE barrier per K-step; stage(k+1) overlaps compute(k).
__global__ __launch_bounds__(256) void gemm_qkv(const u16* __restrict__ h_t,
                                                const u16* __restrict__ wq,
                                                const float* __restrict__ bq,
                                                u16* __restrict__ Qp,
                                                u16* __restrict__ Kp,
                                                u16* __restrict__ Vp) {
  __shared__ u16 Ash[2][128*32];
  __shared__ u16 Bsh[2][128*32];
  const int n0 = blockIdx.x*128, m0 = blockIdx.y*128, b = blockIdx.z;
  const int tid = threadIdx.x, wid = tid >> 6, lane = tid & 63;
  const int wm = wid >> 1, wn = wid & 1;
  const u16* Ag = h_t + (size_t)b*S_N*C_N;
  const f32x4 vzero = {0.f,0.f,0.f,0.f};
  f32x4 acc[4][4];
  #pragma unroll
  for (int i=0;i<4;i++)
    #pragma unroll
    for (int j=0;j<4;j++) acc[i][j] = vzero;

  const int arow = lane >> 2, aslot = (lane & 3) * 8;

  auto stage = [&](u16* Adst, u16* Bdst, int k0s) {
    #pragma unroll
    for (int i = 0; i < 2; i++) {
      int r = wid*32 + i*16 + arow;
      gll16(Ag + (size_t)(m0+r)*C_N + k0s + aslot, &Adst[(wid*32+i*16)*32]);
      gll16(wq + (size_t)(n0+r)*C_N + k0s + aslot, &Bdst[(wid*32+i*16)*32]);
    }
  };
  auto compute = [&](const u16* AshC, const u16* BshC) {
    bf16x8 aF[4], bF[4];
    #pragma unroll
    for (int mi=0;mi<4;mi++)
      aF[mi] = *(const bf16x8*)&AshC[(wm*64+mi*16+(lane&15))*32 + (lane>>4)*8];
    #pragma unroll
    for (int ni=0;ni<4;ni++)
      bF[ni] = *(const bf16x8*)&BshC[(wn*64+ni*16+(lane&15))*32 + (lane>>4)*8];
    #pragma unroll
    for (int mi=0;mi<4;mi++)
      #pragma unroll
      for (int ni=0;ni<4;ni++)
        acc[mi][ni] = __builtin_amdgcn_mfma_f32_16x16x32_bf16(aF[mi], bF[ni], acc[mi][ni], 0, 0, 0);
  };

  stage(Ash[0], Bsh[0], 0);
  #pragma unroll 1
  for (int k0 = 0; k0 < C_N; k0 += 64) {
    asm volatile("s_waitcnt vmcnt(0)" ::: "memory");
    __syncthreads();
    stage(Ash[1], Bsh[1], k0 + 32);
    compute(Ash[0], Bsh[0]);
    asm volatile("s_waitcnt vmcnt(0)" ::: "memory");
    __syncthreads();
    if (k0 + 64 < C_N) stage(Ash[0], Bsh[0], k0 + 64);
    compute(Ash[1], Bsh[1]);
  }

  #pragma unroll
  for (int mi=0;mi<4;mi++) {
    #pragma unroll
    for (int ni=0;ni<4;ni++) {
      int o = n0 + wn*64 + ni*16 + (lane & 15);
      float bias = bq[o];
      int sec = o >> 9;
      int oo  = o & 511;
      int hh  = oo >> 6, d = oo & 63;
      size_t bh = (size_t)(b*NH + hh);
      float qsc = (sec == 0) ? SC2F : 1.0f;
      #pragma unroll
      for (int r=0;r<4;r++) {
        int s = m0 + wm*64 + mi*16 + (lane>>4)*4 + r;
        u16 bv = f2bf((acc[mi][ni][r] + bias) * qsc);
        if (sec == 0)      Qp[(bh*S_N + s)*HD + d] = bv;
        else if (sec == 1) Kp[(bh*S_N + s)*HD + d] = bv;
        else               Vp[(bh*HD + d)*S_N + s] = bv;
      }
    }
  }
}

// ---------------- flash attention: 32x32 swapped, K/V LDS-staged, 1-barrier 2-phase ----------------
// VALU diet: hoisted LDS fragment offsets (loop-invariant), permlane32_swap for the
// P^T half-exchange (no cndmask, no ds_bpermute), ones-MFMA l-sum, no-max softmax.
__device__ __forceinline__ void attn_tile_body(const u16* __restrict__ Kb,
                                               const u16* __restrict__ Vb,
                                               const u16* __restrict__ KlC, const u16* __restrict__ VlC,
                                               u16* __restrict__ KlN, u16* __restrict__ VlN,
                                               const bf16x8 (&qf)[4], const bf16x8 onesf,
                                               f32x16 (&oacc)[2], f32x16& oacc_l,
                                               const int (&off)[2][4],
                                               int it, int hi,
                                               int ra, int rb, int ca, int cb, int wid) {
  const int t0 = it * 64;
  asm volatile("s_waitcnt vmcnt(0)" ::: "memory");   // my slice of tile `it` landed
  __syncthreads();                                    // tile `it` visible; tile it-1 readers closed

  // stage NEXT tile — overlaps all compute below
  if (it < 15) {
    const int tn = t0 + 64;
    gll16(Kb + (size_t)(tn + ra)*HD + ca, &KlN[(wid*16    )*64]);
    gll16(Kb + (size_t)(tn + rb)*HD + cb, &KlN[(wid*16 + 8)*64]);
    gll16(Vb + (size_t)ra*S_N + tn + ca,  &VlN[(wid*16    )*64]);
    gll16(Vb + (size_t)rb*S_N + tn + cb,  &VlN[(wid*16 + 8)*64]);
  }

  // K fragments via hoisted offsets
  bf16x8 kF[2][4];
  #pragma unroll
  for (int tt=0;tt<2;tt++)
    #pragma unroll
    for (int kt=0;kt<4;kt++)
      kF[tt][kt] = *(const bf16x8*)&KlC[off[tt][kt]];

  // QK^T: st[tt][reg] = S[t][s], t=(reg&3)+8*(reg>>2)+4*hi+32*tt
  f32x16 st[2];
  #pragma unroll
  for (int tt=0;tt<2;tt++)
    #pragma unroll
    for (int i=0;i<16;i++) st[tt][i] = 0.f;
  __builtin_amdgcn_s_setprio(1);
  #pragma unroll
  for (int tt=0;tt<2;tt++)
    #pragma unroll
    for (int kt=0;kt<4;kt++)
      st[tt] = __builtin_amdgcn_mfma_f32_32x32x16_bf16(kF[tt][kt], qf[kt], st[tt], 0, 0, 0);
  __builtin_amdgcn_s_setprio(0);

  // p = exp2(S) in place (Q pre-scaled)
  #pragma unroll
  for (int tt=0;tt<2;tt++)
    #pragma unroll
    for (int i=0;i<16;i++)
      st[tt][i] = exp2f(st[tt][i]);

  // P^T B-fragments via permlane32_swap:
  // swap(w0,w2): out_a = [w0.lo, w2.lo] = frag word0 ; out_b = [w0.hi, w2.hi] = frag word2
  u32x4 paw[4];
  #pragma unroll
  for (int ks=0;ks<4;ks++) {
    u32 w0 = cvtpk(st[ks>>1][(ks&1)*8+0], st[ks>>1][(ks&1)*8+1]);
    u32 w1 = cvtpk(st[ks>>1][(ks&1)*8+2], st[ks>>1][(ks&1)*8+3]);
    u32 w2 = cvtpk(st[ks>>1][(ks&1)*8+4], st[ks>>1][(ks&1)*8+5]);
    u32 w3 = cvtpk(st[ks>>1][(ks&1)*8+6], st[ks>>1][(ks&1)*8+7]);
    asm("v_permlane32_swap_b32 %0, %1" : "+v"(w0), "+v"(w2));
    asm("v_permlane32_swap_b32 %0, %1" : "+v"(w1), "+v"(w3));
    u32x4 w = { w0, w1, w2, w3 };
    paw[ks] = w;
  }

  // PV + l-sum: V fragments via hoisted offsets; l via ones-MFMA
  __builtin_amdgcn_s_setprio(1);
  #pragma unroll
  for (int ks=0;ks<4;ks++) {
    bf16x8 pb = __builtin_bit_cast(bf16x8, paw[ks]);
    oacc_l = __builtin_amdgcn_mfma_f32_32x32x16_bf16(onesf, pb, oacc_l, 0, 0, 0);
    #pragma unroll
    for (int dt=0;dt<2;dt++) {
      bf16x8 vF = *(const bf16x8*)&VlC[off[dt][ks]];
      oacc[dt] = __builtin_amdgcn_mfma_f32_32x32x16_bf16(vF, pb, oacc[dt], 0, 0, 0);
    }
  }
  __builtin_amdgcn_s_setprio(0);
  // no trailing barrier: next iter's {vmcnt; barrier} closes this tile's reads
}

__global__ __launch_bounds__(256) void attn_fwd(const u16* __restrict__ Qp,
                                                const u16* __restrict__ Kp,
                                                const u16* __restrict__ Vp,
                                                u16* __restrict__ at) {
  __shared__ u16 Kl[2][64*64];   // [t][d] rows 128B, 16B-slot XOR'd by (t&7)
  __shared__ u16 Vl[2][64*64];   // [d][t] rows 128B, 16B-slot XOR'd by (d&7)
  const int hh = blockIdx.x, q0 = blockIdx.y*128, b = blockIdx.z;
  const int tid = threadIdx.x, wid = tid >> 6, lane = tid & 63;
  const int l31 = lane & 31, hi = lane >> 5;
  const size_t bh = (size_t)(b*NH + hh);
  const u16* Qb = Qp + bh*(S_N*HD);
  const u16* Kb = Kp + bh*(S_N*HD);
  const u16* Vb = Vp + bh*(HD*S_N);
  const int s = q0 + wid*32 + l31;          // this lane's s-row

  // Q B-fragments: Q[s][kt*16 + hi*8 + j]
  bf16x8 qf[4];
  #pragma unroll
  for (int kt=0;kt<4;kt++)
    qf[kt] = *(const bf16x8*)&Qb[(size_t)s*HD + kt*16 + hi*8];

  const u32x4 onesw = {0x3F803F80u, 0x3F803F80u, 0x3F803F80u, 0x3F803F80u};
  const bf16x8 onesf = __builtin_bit_cast(bf16x8, onesw);

  f32x16 oacc[2], oacc_l;
  #pragma unroll
  for (int dt=0;dt<2;dt++)
    #pragma unroll
    for (int i=0;i<16;i++) oacc[dt][i] = 0.f;
  #pragma unroll
  for (int i=0;i<16;i++) oacc_l[i] = 0.f;

  // hoisted LDS fragment element-offsets (same for K and V: row = g*32+l31)
  int off[2][4];
  #pragma unroll
  for (int g=0; g<2; g++)
    #pragma unroll
    for (int kt=0; kt<4; kt++) {
      int row = g*32 + l31;
      int phys = (kt*2 + hi) ^ (row & 7);
      off[g][kt] = row*64 + phys*8;
    }

  // staging geometry: row = wid*16 + {0,8} + (lane>>3), source slot = (lane&7)^(row&7)
  const int ra = wid*16 + (lane >> 3);
  const int rb = ra + 8;
  const int ca = (((lane & 7) ^ (ra & 7)) * 8);
  const int cb = (((lane & 7) ^ (rb & 7)) * 8);

  // prologue: stage tile 0 into buffer 0
  gll16(Kb + (size_t)ra*HD + ca,  &Kl[0][(wid*16    )*64]);
  gll16(Kb + (size_t)rb*HD + cb,  &Kl[0][(wid*16 + 8)*64]);
  gll16(Vb + (size_t)ra*S_N + ca, &Vl[0][(wid*16    )*64]);
  gll16(Vb + (size_t)rb*S_N + cb, &Vl[0][(wid*16 + 8)*64]);

  #pragma unroll 1
  for (int it = 0; it < 16; it += 2) {
    attn_tile_body(Kb, Vb, Kl[0], Vl[0], Kl[1], Vl[1], qf, onesf, oacc, oacc_l, off,
                   it,     hi, ra, rb, ca, cb, wid);
    attn_tile_body(Kb, Vb, Kl[1], Vl[1], Kl[0], Vl[0], qf, onesf, oacc, oacc_l, off,
                   it + 1, hi, ra, rb, ca, cb, wid);
  }

  // l is complete (ones-MFMA contracts both halves); all oacc_l regs identical
  float inv = 1.0f / oacc_l[0];
  #pragma unroll
  for (int dt=0;dt<2;dt++)
    #pragma unroll
    for (int qd=0;qd<4;qd++) {
      int dbase = 4*hi + 8*qd + 32*dt;
      u16x4 o;
      #pragma unroll
      for (int j=0;j<4;j++) o[j] = f2bf(oacc[dt][qd*4+j] * inv);
      *(u16x4*)&at[((size_t)b*S_N + s)*C_N + hh*HD + dbase] = o;
    }
}

// ---------------- GEMM-2: out = proj_w @ attn + bias + x ----------------
// Double-buffered LDS, ONE barrier per K-step; stage(k+1) overlaps compute(k).
__global__ __launch_bounds__(256) void gemm_proj(const u16* __restrict__ pwb,
                                                 const u16* __restrict__ at,
                                                 const float* __restrict__ bp,
                                                 const float* __restrict__ x,
                                                 float* __restrict__ out) {
  __shared__ u16 Ash[2][128*32];
  __shared__ u16 Bsh[2][128*32];
  const int n0 = blockIdx.x*128, m0 = blockIdx.y*128, b = blockIdx.z;
  const int tid = threadIdx.x, wid = tid >> 6, lane = tid & 63;
  const int wm = wid >> 1, wn = wid & 1;
  const u16* Bg = at + (size_t)b*S_N*C_N;
  const f32x4 vzero = {0.f,0.f,0.f,0.f};
  f32x4 acc[4][4];
  #pragma unroll
  for (int i=0;i<4;i++)
    #pragma unroll
    for (int j=0;j<4;j++) acc[i][j] = vzero;

  const int arow = lane >> 2, aslot = (lane & 3) * 8;

  auto stage = [&](u16* Adst, u16* Bdst, int k0s) {
    #pragma unroll
    for (int i = 0; i < 2; i++) {
      int r = wid*32 + i*16 + arow;
      gll16(pwb + (size_t)(m0+r)*C_N + k0s + aslot, &Adst[(wid*32+i*16)*32]);
      gll16(Bg  + (size_t)(n0+r)*C_N + k0s + aslot, &Bdst[(wid*32+i*16)*32]);
    }
  };
  auto compute = [&](const u16* AshC, const u16* BshC) {
    bf16x8 aF[4], bF[4];
    #pragma unroll
    for (int mi=0;mi<4;mi++)
      aF[mi] = *(const bf16x8*)&AshC[(wm*64+mi*16+(lane&15))*32 + (lane>>4)*8];
    #pragma unroll
    for (int ni=0;ni<4;ni++)
      bF[ni] = *(const bf16x8*)&BshC[(wn*64+ni*16+(lane&15))*32 + (lane>>4)*8];
    #pragma unroll
    for (int mi=0;mi<4;mi++)
      #pragma unroll
      for (int ni=0;ni<4;ni++)
        acc[mi][ni] = __builtin_amdgcn_mfma_f32_16x16x32_bf16(aF[mi], bF[ni], acc[mi][ni], 0, 0, 0);
  };

  stage(Ash[0], Bsh[0], 0);
  #pragma unroll 1
  for (int k0 = 0; k0 < C_N; k0 += 64) {
    asm volatile("s_waitcnt vmcnt(0)" ::: "memory");
    __syncthreads();
    stage(Ash[1], Bsh[1], k0 + 32);
    compute(Ash[0], Bsh[0]);
    asm volatile("s_waitcnt vmcnt(0)" ::: "memory");
    __syncthreads();
    if (k0 + 64 < C_N) stage(Ash[0], Bsh[0], k0 + 64);
    compute(Ash[1], Bsh[1]);
  }

  #pragma unroll
  for (int mi=0;mi<4;mi++) {
    #pragma unroll
    for (int ni=0;ni<4;ni++) {
      int ss = n0 + wn*64 + ni*16 + (lane & 15);
      #pragma unroll
      for (int r=0;r<4;r++) {
        int o = m0 + wm*64 + mi*16 + (lane>>4)*4 + r;
        size_t idx = ((size_t)b*C_N + o)*S_N + ss;
        out[idx] = acc[mi][ni][r] + bp[o] + x[idx];
      }
    }
  }
}

extern "C" void kernel_launch(void* const* d_in, const int* in_sizes, int n_in,
                              void* d_out, int out_size, void* d_ws, size_t ws_size,
                              hipStream_t stream) {
  const float* x     = (const float*)d_in[0];
  const float* nw    = (const float*)d_in[1];
  const float* nb    = (const float*)d_in[2];
  const float* qkvw  = (const float*)d_in[3];
  const float* qkvb  = (const float*)d_in[4];
  const float* projw = (const float*)d_in[5];
  const float* projb = (const float*)d_in[6];
  float* out = (float*)d_out;

  char* ws = (char*)d_ws;
  float* stats = (float*)ws;                              //   4 KB
  u16* h_t = (u16*)(ws + 4096);                           //  16 MB  [B][S][C]
  u16* qw  = (u16*)(ws + 4096 + 16777216);                // 1.5 MB  [1536][512]
  u16* pw  = (u16*)((char*)qw + 1572864);                 // 0.5 MB  [512][512]
  u16* Qp  = (u16*)((char*)pw + 524288);                  //  16 MB  [B][NH][S][HD]
  u16* Kp  = (u16*)((char*)Qp + 16777216);                //  16 MB  [B][NH][S][HD]
  u16* Vp  = (u16*)((char*)Kp + 16777216);                //  16 MB  [B][NH][HD][S]
  u16* at  = (u16*)((char*)Vp + 16777216);                //  16 MB  [B][S][C]

  gn_stats_cvt<<<1536, 256, 0, stream>>>(x, stats, qkvw, projw, qw, pw);
  gn_apply_t  <<<dim3(16,16,16), 256, 0, stream>>>(x, stats, nw, nb, h_t);
  gemm_qkv    <<<dim3(12,8,16), 256, 0, stream>>>(h_t, qw, qkvb, Qp, Kp, Vp);
  attn_fwd    <<<dim3(8,8,16), 256, 0, stream>>>(Qp, Kp, Vp, at);
  gemm_proj   <<<dim3(8,4,16), 256, 0, stream>>>(pw, at, projb, x, out);
}

// Round 14
// 248.367 us; speedup vs baseline: 1.0454x; 1.0267x over previous
//
#include <hip/hip_runtime.h>
#include <hip/hip_bf16.h>
#include <stdint.h>

#define B_N 16
#define C_N 512
#define S_N 1024
#define G_N 32
#define NH  8
#define HD  64

typedef __attribute__((ext_vector_type(8))) short bf16x8;
typedef __attribute__((ext_vector_type(4))) float f32x4;
typedef __attribute__((ext_vector_type(16))) float f32x16;
typedef unsigned short u16;
typedef unsigned int   u32;
typedef __attribute__((ext_vector_type(4))) u16 u16x4;
typedef __attribute__((ext_vector_type(4))) u32 u32x4;

#define SC2F 0.18033688011112042f   // (1/sqrt(64)) * log2(e), folded into Q

__device__ __forceinline__ u16 f2bf(float f) {
  u32 u = __builtin_bit_cast(u32, f);
  u32 r = (u + 0x7fffu + ((u >> 16) & 1u)) >> 16;   // RNE
  return (u16)r;
}

// single-instruction packed f32x2 -> bf16x2 (a -> low 16, b -> high 16)
__device__ __forceinline__ u32 cvtpk(float a, float b) {
  u32 r;
  asm("v_cvt_pk_bf16_f32 %0, %1, %2" : "=v"(r) : "v"(a), "v"(b));
  return r;
}

__device__ __forceinline__ void gll16(const void* g, void* l) {
  __builtin_amdgcn_global_load_lds((const __attribute__((address_space(1))) u32*)g,
                                   (__attribute__((address_space(3))) u32*)l, 16, 0, 0);
}

// ---------------- GroupNorm stats (blocks 0..511) + weight bf16 convert (blocks 512..1535) ----------------
__global__ __launch_bounds__(256) void gn_stats_cvt(const float* __restrict__ x,
                                                    float* __restrict__ stats,
                                                    const float* __restrict__ qkvw,
                                                    const float* __restrict__ projw,
                                                    u16* __restrict__ qw,
                                                    u16* __restrict__ pw) {
  const int blk = blockIdx.x;
  if (blk < 512) {
    const int bg = blk;                         // b*32+g
    const float4* xv = (const float4*)(x + (size_t)bg * (16 * S_N));
    float s = 0.f, ss = 0.f;
    for (int i = threadIdx.x; i < 4096; i += 256) {
      float4 v = xv[i];
      s  += v.x + v.y + v.z + v.w;
      ss += v.x*v.x + v.y*v.y + v.z*v.z + v.w*v.w;
    }
    #pragma unroll
    for (int m = 1; m < 64; m <<= 1) { s += __shfl_xor(s, m); ss += __shfl_xor(ss, m); }
    __shared__ float red[2][4];
    const int wid = threadIdx.x >> 6;
    if ((threadIdx.x & 63) == 0) { red[0][wid] = s; red[1][wid] = ss; }
    __syncthreads();
    if (threadIdx.x == 0) {
      float S1 = red[0][0]+red[0][1]+red[0][2]+red[0][3];
      float S2 = red[1][0]+red[1][1]+red[1][2]+red[1][3];
      float mean = S1 * (1.f/16384.f);
      float var  = S2 * (1.f/16384.f) - mean*mean;
      stats[bg*2]   = mean;
      stats[bg*2+1] = rsqrtf(var + 1e-5f);
    }
  } else {
    int i = (blk - 512)*256 + threadIdx.x;      // exactly 262144 = 196608 + 65536
    const float4* src; u16x4* dst; int j;
    if (i < 196608) { src = (const float4*)qkvw;  dst = (u16x4*)qw; j = i; }
    else            { src = (const float4*)projw; dst = (u16x4*)pw; j = i - 196608; }
    float4 v = src[j];
    u16x4 r = { f2bf(v.x), f2bf(v.y), f2bf(v.z), f2bf(v.w) };
    dst[j] = r;
  }
}

// ------------- normalize + transpose -> h_t[b][s][c] (bf16) -------------
__global__ __launch_bounds__(256) void gn_apply_t(const float* __restrict__ x,
                                                  const float* __restrict__ stats,
                                                  const float* __restrict__ nw,
                                                  const float* __restrict__ nb,
                                                  u16* __restrict__ h_t) {
  const int c0 = blockIdx.x * 32, s0 = blockIdx.y * 64, b = blockIdx.z;
  __shared__ u16 tile[32][68];
  const int t = threadIdx.x;
  #pragma unroll
  for (int i = 0; i < 2; i++) {
    int idx4 = (i*256 + t) * 4;
    int cr = idx4 >> 6, sr = idx4 & 63;
    int c = c0 + cr;
    float4 v = *(const float4*)&x[((size_t)b*C_N + c)*S_N + s0 + sr];
    int bg = b*G_N + (c >> 4);
    float mean = stats[bg*2], rstd = stats[bg*2+1];
    float w = nw[c]*rstd;
    float bb = nb[c] - mean*w;
    tile[cr][sr]   = f2bf(v.x*w + bb);
    tile[cr][sr+1] = f2bf(v.y*w + bb);
    tile[cr][sr+2] = f2bf(v.z*w + bb);
    tile[cr][sr+3] = f2bf(v.w*w + bb);
  }
  __syncthreads();
  #pragma unroll
  for (int i = 0; i < 2; i++) {
    int idx = i*256 + t;
    int sr = idx >> 3;
    int cr4 = (idx & 7) * 4;
    u16x4 v = { tile[cr4][sr], tile[cr4+1][sr], tile[cr4+2][sr], tile[cr4+3][sr] };
    *(u16x4*)&h_t[((size_t)b*S_N + s0 + sr)*C_N + c0 + cr4] = v;
  }
}

// ---------------- GEMM-1: qkv = h_t @ qkv_w^T, scatter to Q/K/V packs ----------------
// 3-buffer ring, counted vmcnt(4): loads for tile i issued 2 K-steps before use.
// LDS slot^(row&3) swizzle (inverse-swizzled gll16 source). XCD-swizzled grid.
__global__ __launch_bounds__(256) void gemm_qkv(const u16* __restrict__ h_t,
                                                const u16* __restrict__ wq,
                                                const float* __restrict__ bq,
                                                u16* __restrict__ Qp,
                                                u16* __restrict__ Kp,
                                                u16* __restrict__ Vp) {
  __shared__ u16 Ash[3][128*32];
  __shared__ u16 Bsh[3][128*32];
  // bijective XCD swizzle: nwg = 1536 (%8==0), cpx = 192
  const int lin = blockIdx.x + blockIdx.y*12 + blockIdx.z*96;
  const int swz = (lin & 7)*192 + (lin >> 3);
  const int n0 = (swz % 12)*128, m0 = ((swz/12) & 7)*128, b = swz/96;
  const int tid = threadIdx.x, wid = tid >> 6, lane = tid & 63;
  const int wm = wid >> 1, wn = wid & 1;
  const u16* Ag = h_t + (size_t)b*S_N*C_N;
  const f32x4 vzero = {0.f,0.f,0.f,0.f};
  f32x4 acc[4][4];
  #pragma unroll
  for (int i=0;i<4;i++)
    #pragma unroll
    for (int j=0;j<4;j++) acc[i][j] = vzero;

  // staging: lane -> row (lane>>2), phys slot (lane&3); source k-slot inverse-swizzled
  const int arow = lane >> 2;
  const int cs = (((lane & 3) ^ ((lane >> 2) & 3)) * 8);
  // read fragments: row = w*64+f*16+(lane&15), logical slot lane>>4, phys = (lane>>4)^(row&3)
  int offA[4], offB[4];
  #pragma unroll
  for (int f=0; f<4; f++) {
    int rowa = wm*64 + f*16 + (lane & 15);
    int rowb = wn*64 + f*16 + (lane & 15);
    offA[f] = rowa*32 + (((lane>>4) ^ (rowa & 3))*8);
    offB[f] = rowb*32 + (((lane>>4) ^ (rowb & 3))*8);
  }

  auto stage = [&](u16* Adst, u16* Bdst, int k0s) {
    #pragma unroll
    for (int i = 0; i < 2; i++) {
      int r = wid*32 + i*16 + arow;
      gll16(Ag + (size_t)(m0+r)*C_N + k0s + cs, Adst + (wid*32+i*16)*32);
      gll16(wq + (size_t)(n0+r)*C_N + k0s + cs, Bdst + (wid*32+i*16)*32);
    }
  };
  auto compute = [&](const u16* AshC, const u16* BshC) {
    bf16x8 aF[4], bF[4];
    #pragma unroll
    for (int mi=0;mi<4;mi++) aF[mi] = *(const bf16x8*)&AshC[offA[mi]];
    #pragma unroll
    for (int ni=0;ni<4;ni++) bF[ni] = *(const bf16x8*)&BshC[offB[ni]];
    #pragma unroll
    for (int mi=0;mi<4;mi++)
      #pragma unroll
      for (int ni=0;ni<4;ni++)
        acc[mi][ni] = __builtin_amdgcn_mfma_f32_16x16x32_bf16(aF[mi], bF[ni], acc[mi][ni], 0, 0, 0);
  };

  u16 *A0=&Ash[0][0], *A1=&Ash[1][0], *A2=&Ash[2][0];
  u16 *B0=&Bsh[0][0], *B1=&Bsh[1][0], *B2=&Bsh[2][0];
  stage(A0, B0, 0);
  stage(A1, B1, 32);
  #pragma unroll 1
  for (int i = 0; i < 15; i++) {
    asm volatile("s_waitcnt vmcnt(4)" ::: "memory");   // oldest stage (tile i) landed
    __syncthreads();
    if (i < 14) stage(A2, B2, (i+2)*32);
    compute(A0, B0);
    u16* t;
    t=A0; A0=A1; A1=A2; A2=t;
    t=B0; B0=B1; B1=B2; B2=t;
  }
  asm volatile("s_waitcnt vmcnt(0)" ::: "memory");
  __syncthreads();
  compute(A0, B0);

  #pragma unroll
  for (int mi=0;mi<4;mi++) {
    #pragma unroll
    for (int ni=0;ni<4;ni++) {
      int o = n0 + wn*64 + ni*16 + (lane & 15);
      float bias = bq[o];
      int sec = o >> 9;
      int oo  = o & 511;
      int hh  = oo >> 6, d = oo & 63;
      size_t bh = (size_t)(b*NH + hh);
      float qsc = (sec == 0) ? SC2F : 1.0f;
      #pragma unroll
      for (int r=0;r<4;r++) {
        int s = m0 + wm*64 + mi*16 + (lane>>4)*4 + r;
        u16 bv = f2bf((acc[mi][ni][r] + bias) * qsc);
        if (sec == 0)      Qp[(bh*S_N + s)*HD + d] = bv;
        else if (sec == 1) Kp[(bh*S_N + s)*HD + d] = bv;
        else               Vp[(bh*HD + d)*S_N + s] = bv;
      }
    }
  }
}

// ---------------- flash attention: 32x32 swapped, K/V LDS-staged, 1-barrier 2-phase ----------------
__device__ __forceinline__ void attn_tile_body(const u16* __restrict__ Kb,
                                               const u16* __restrict__ Vb,
                                               const u16* __restrict__ KlC, const u16* __restrict__ VlC,
                                               u16* __restrict__ KlN, u16* __restrict__ VlN,
                                               const bf16x8 (&qf)[4], const bf16x8 onesf,
                                               f32x16 (&oacc)[2], f32x16& oacc_l,
                                               const int (&off)[2][4],
                                               int it, int hi,
                                               int ra, int rb, int ca, int cb, int wid) {
  const int t0 = it * 64;
  asm volatile("s_waitcnt vmcnt(0)" ::: "memory");   // my slice of tile `it` landed
  __syncthreads();                                    // tile `it` visible; tile it-1 readers closed

  // stage NEXT tile — overlaps all compute below
  if (it < 15) {
    const int tn = t0 + 64;
    gll16(Kb + (size_t)(tn + ra)*HD + ca, &KlN[(wid*16    )*64]);
    gll16(Kb + (size_t)(tn + rb)*HD + cb, &KlN[(wid*16 + 8)*64]);
    gll16(Vb + (size_t)ra*S_N + tn + ca,  &VlN[(wid*16    )*64]);
    gll16(Vb + (size_t)rb*S_N + tn + cb,  &VlN[(wid*16 + 8)*64]);
  }

  // K fragments via hoisted offsets
  bf16x8 kF[2][4];
  #pragma unroll
  for (int tt=0;tt<2;tt++)
    #pragma unroll
    for (int kt=0;kt<4;kt++)
      kF[tt][kt] = *(const bf16x8*)&KlC[off[tt][kt]];

  // QK^T: st[tt][reg] = S[t][s], t=(reg&3)+8*(reg>>2)+4*hi+32*tt
  f32x16 st[2];
  #pragma unroll
  for (int tt=0;tt<2;tt++)
    #pragma unroll
    for (int i=0;i<16;i++) st[tt][i] = 0.f;
  __builtin_amdgcn_s_setprio(1);
  #pragma unroll
  for (int tt=0;tt<2;tt++)
    #pragma unroll
    for (int kt=0;kt<4;kt++)
      st[tt] = __builtin_amdgcn_mfma_f32_32x32x16_bf16(kF[tt][kt], qf[kt], st[tt], 0, 0, 0);
  __builtin_amdgcn_s_setprio(0);

  // p = exp2(S) in place (Q pre-scaled)
  #pragma unroll
  for (int tt=0;tt<2;tt++)
    #pragma unroll
    for (int i=0;i<16;i++)
      st[tt][i] = exp2f(st[tt][i]);

  // P^T B-fragments via permlane32_swap
  u32x4 paw[4];
  #pragma unroll
  for (int ks=0;ks<4;ks++) {
    u32 w0 = cvtpk(st[ks>>1][(ks&1)*8+0], st[ks>>1][(ks&1)*8+1]);
    u32 w1 = cvtpk(st[ks>>1][(ks&1)*8+2], st[ks>>1][(ks&1)*8+3]);
    u32 w2 = cvtpk(st[ks>>1][(ks&1)*8+4], st[ks>>1][(ks&1)*8+5]);
    u32 w3 = cvtpk(st[ks>>1][(ks&1)*8+6], st[ks>>1][(ks&1)*8+7]);
    asm("v_permlane32_swap_b32 %0, %1" : "+v"(w0), "+v"(w2));
    asm("v_permlane32_swap_b32 %0, %1" : "+v"(w1), "+v"(w3));
    u32x4 w = { w0, w1, w2, w3 };
    paw[ks] = w;
  }

  // PV + l-sum: V fragments via hoisted offsets; l via ones-MFMA
  __builtin_amdgcn_s_setprio(1);
  #pragma unroll
  for (int ks=0;ks<4;ks++) {
    bf16x8 pb = __builtin_bit_cast(bf16x8, paw[ks]);
    oacc_l = __builtin_amdgcn_mfma_f32_32x32x16_bf16(onesf, pb, oacc_l, 0, 0, 0);
    #pragma unroll
    for (int dt=0;dt<2;dt++) {
      bf16x8 vF = *(const bf16x8*)&VlC[off[dt][ks]];
      oacc[dt] = __builtin_amdgcn_mfma_f32_32x32x16_bf16(vF, pb, oacc[dt], 0, 0, 0);
    }
  }
  __builtin_amdgcn_s_setprio(0);
}

__global__ __launch_bounds__(256) void attn_fwd(const u16* __restrict__ Qp,
                                                const u16* __restrict__ Kp,
                                                const u16* __restrict__ Vp,
                                                u16* __restrict__ at) {
  __shared__ u16 Kl[2][64*64];
  __shared__ u16 Vl[2][64*64];
  const int hh = blockIdx.x, q0 = blockIdx.y*128, b = blockIdx.z;
  const int tid = threadIdx.x, wid = tid >> 6, lane = tid & 63;
  const int l31 = lane & 31, hi = lane >> 5;
  const size_t bh = (size_t)(b*NH + hh);
  const u16* Qb = Qp + bh*(S_N*HD);
  const u16* Kb = Kp + bh*(S_N*HD);
  const u16* Vb = Vp + bh*(HD*S_N);
  const int s = q0 + wid*32 + l31;

  bf16x8 qf[4];
  #pragma unroll
  for (int kt=0;kt<4;kt++)
    qf[kt] = *(const bf16x8*)&Qb[(size_t)s*HD + kt*16 + hi*8];

  const u32x4 onesw = {0x3F803F80u, 0x3F803F80u, 0x3F803F80u, 0x3F803F80u};
  const bf16x8 onesf = __builtin_bit_cast(bf16x8, onesw);

  f32x16 oacc[2], oacc_l;
  #pragma unroll
  for (int dt=0;dt<2;dt++)
    #pragma unroll
    for (int i=0;i<16;i++) oacc[dt][i] = 0.f;
  #pragma unroll
  for (int i=0;i<16;i++) oacc_l[i] = 0.f;

  int off[2][4];
  #pragma unroll
  for (int g=0; g<2; g++)
    #pragma unroll
    for (int kt=0; kt<4; kt++) {
      int row = g*32 + l31;
      int phys = (kt*2 + hi) ^ (row & 7);
      off[g][kt] = row*64 + phys*8;
    }

  const int ra = wid*16 + (lane >> 3);
  const int rb = ra + 8;
  const int ca = (((lane & 7) ^ (ra & 7)) * 8);
  const int cb = (((lane & 7) ^ (rb & 7)) * 8);

  gll16(Kb + (size_t)ra*HD + ca,  &Kl[0][(wid*16    )*64]);
  gll16(Kb + (size_t)rb*HD + cb,  &Kl[0][(wid*16 + 8)*64]);
  gll16(Vb + (size_t)ra*S_N + ca, &Vl[0][(wid*16    )*64]);
  gll16(Vb + (size_t)rb*S_N + cb, &Vl[0][(wid*16 + 8)*64]);

  #pragma unroll 1
  for (int it = 0; it < 16; it += 2) {
    attn_tile_body(Kb, Vb, Kl[0], Vl[0], Kl[1], Vl[1], qf, onesf, oacc, oacc_l, off,
                   it,     hi, ra, rb, ca, cb, wid);
    attn_tile_body(Kb, Vb, Kl[1], Vl[1], Kl[0], Vl[0], qf, onesf, oacc, oacc_l, off,
                   it + 1, hi, ra, rb, ca, cb, wid);
  }

  float inv = 1.0f / oacc_l[0];
  #pragma unroll
  for (int dt=0;dt<2;dt++)
    #pragma unroll
    for (int qd=0;qd<4;qd++) {
      int dbase = 4*hi + 8*qd + 32*dt;
      u16x4 o;
      #pragma unroll
      for (int j=0;j<4;j++) o[j] = f2bf(oacc[dt][qd*4+j] * inv);
      *(u16x4*)&at[((size_t)b*S_N + s)*C_N + hh*HD + dbase] = o;
    }
}

// ---------------- GEMM-2: out = proj_w @ attn + bias + x ----------------
// Same 3-buffer counted-vmcnt ring + swizzles as GEMM-1.
__global__ __launch_bounds__(256) void gemm_proj(const u16* __restrict__ pwb,
                                                 const u16* __restrict__ at,
                                                 const float* __restrict__ bp,
                                                 const float* __restrict__ x,
                                                 float* __restrict__ out) {
  __shared__ u16 Ash[3][128*32];
  __shared__ u16 Bsh[3][128*32];
  // bijective XCD swizzle: nwg = 512 (%8==0), cpx = 64
  const int lin = blockIdx.x + blockIdx.y*8 + blockIdx.z*32;
  const int swz = (lin & 7)*64 + (lin >> 3);
  const int n0 = (swz & 7)*128, m0 = ((swz >> 3) & 3)*128, b = swz >> 5;
  const int tid = threadIdx.x, wid = tid >> 6, lane = tid & 63;
  const int wm = wid >> 1, wn = wid & 1;
  const u16* Bg = at + (size_t)b*S_N*C_N;
  const f32x4 vzero = {0.f,0.f,0.f,0.f};
  f32x4 acc[4][4];
  #pragma unroll
  for (int i=0;i<4;i++)
    #pragma unroll
    for (int j=0;j<4;j++) acc[i][j] = vzero;

  const int arow = lane >> 2;
  const int cs = (((lane & 3) ^ ((lane >> 2) & 3)) * 8);
  int offA[4], offB[4];
  #pragma unroll
  for (int f=0; f<4; f++) {
    int rowa = wm*64 + f*16 + (lane & 15);
    int rowb = wn*64 + f*16 + (lane & 15);
    offA[f] = rowa*32 + (((lane>>4) ^ (rowa & 3))*8);
    offB[f] = rowb*32 + (((lane>>4) ^ (rowb & 3))*8);
  }

  auto stage = [&](u16* Adst, u16* Bdst, int k0s) {
    #pragma unroll
    for (int i = 0; i < 2; i++) {
      int r = wid*32 + i*16 + arow;
      gll16(pwb + (size_t)(m0+r)*C_N + k0s + cs, Adst + (wid*32+i*16)*32);
      gll16(Bg  + (size_t)(n0+r)*C_N + k0s + cs, Bdst + (wid*32+i*16)*32);
    }
  };
  auto compute = [&](const u16* AshC, const u16* BshC) {
    bf16x8 aF[4], bF[4];
    #pragma unroll
    for (int mi=0;mi<4;mi++) aF[mi] = *(const bf16x8*)&AshC[offA[mi]];
    #pragma unroll
    for (int ni=0;ni<4;ni++) bF[ni] = *(const bf16x8*)&BshC[offB[ni]];
    #pragma unroll
    for (int mi=0;mi<4;mi++)
      #pragma unroll
      for (int ni=0;ni<4;ni++)
        acc[mi][ni] = __builtin_amdgcn_mfma_f32_16x16x32_bf16(aF[mi], bF[ni], acc[mi][ni], 0, 0, 0);
  };

  u16 *A0=&Ash[0][0], *A1=&Ash[1][0], *A2=&Ash[2][0];
  u16 *B0=&Bsh[0][0], *B1=&Bsh[1][0], *B2=&Bsh[2][0];
  stage(A0, B0, 0);
  stage(A1, B1, 32);
  #pragma unroll 1
  for (int i = 0; i < 15; i++) {
    asm volatile("s_waitcnt vmcnt(4)" ::: "memory");
    __syncthreads();
    if (i < 14) stage(A2, B2, (i+2)*32);
    compute(A0, B0);
    u16* t;
    t=A0; A0=A1; A1=A2; A2=t;
    t=B0; B0=B1; B1=B2; B2=t;
  }
  asm volatile("s_waitcnt vmcnt(0)" ::: "memory");
  __syncthreads();
  compute(A0, B0);

  #pragma unroll
  for (int mi=0;mi<4;mi++) {
    #pragma unroll
    for (int ni=0;ni<4;ni++) {
      int ss = n0 + wn*64 + ni*16 + (lane & 15);
      #pragma unroll
      for (int r=0;r<4;r++) {
        int o = m0 + wm*64 + mi*16 + (lane>>4)*4 + r;
        size_t idx = ((size_t)b*C_N + o)*S_N + ss;
        out[idx] = acc[mi][ni][r] + bp[o] + x[idx];
      }
    }
  }
}

extern "C" void kernel_launch(void* const* d_in, const int* in_sizes, int n_in,
                              void* d_out, int out_size, void* d_ws, size_t ws_size,
                              hipStream_t stream) {
  const float* x     = (const float*)d_in[0];
  const float* nw    = (const float*)d_in[1];
  const float* nb    = (const float*)d_in[2];
  const float* qkvw  = (const float*)d_in[3];
  const float* qkvb  = (const float*)d_in[4];
  const float* projw = (const float*)d_in[5];
  const float* projb = (const float*)d_in[6];
  float* out = (float*)d_out;

  char* ws = (char*)d_ws;
  float* stats = (float*)ws;                              //   4 KB
  u16* h_t = (u16*)(ws + 4096);                           //  16 MB  [B][S][C]
  u16* qw  = (u16*)(ws + 4096 + 16777216);                // 1.5 MB  [1536][512]
  u16* pw  = (u16*)((char*)qw + 1572864);                 // 0.5 MB  [512][512]
  u16* Qp  = (u16*)((char*)pw + 524288);                  //  16 MB  [B][NH][S][HD]
  u16* Kp  = (u16*)((char*)Qp + 16777216);                //  16 MB  [B][NH][S][HD]
  u16* Vp  = (u16*)((char*)Kp + 16777216);                //  16 MB  [B][NH][HD][S]
  u16* at  = (u16*)((char*)Vp + 16777216);                //  16 MB  [B][S][C]

  gn_stats_cvt<<<1536, 256, 0, stream>>>(x, stats, qkvw, projw, qw, pw);
  gn_apply_t  <<<dim3(16,16,16), 256, 0, stream>>>(x, stats, nw, nb, h_t);
  gemm_qkv    <<<dim3(12,8,16), 256, 0, stream>>>(h_t, qw, qkvb, Qp, Kp, Vp);
  attn_fwd    <<<dim3(8,8,16), 256, 0, stream>>>(Qp, Kp, Vp, at);
  gemm_proj   <<<dim3(8,4,16), 256, 0, stream>>>(pw, at, projb, x, out);
}